// Round 2
// baseline (551.329 us; speedup 1.0000x reference)
//
#include <hip/hip_runtime.h>

// Convattn: B=16, N=740 (256+484), C=768, H=12, hd=64. Inputs/outputs fp32.
// ws: XB/QB/Q/K/V/CTX bf16 (V aliases QB — safe ONLY because Q-GEMM and
// KV-GEMM are separate ordered launches; do NOT fuse them), BIAS2 bf16
// repacked [h][row][jb][ln][nt], WT bf16 (q-plane pre-scaled 0.125).

typedef unsigned short u16;
typedef short bf16x8 __attribute__((ext_vector_type(8)));
typedef float f32x4 __attribute__((ext_vector_type(4)));

#define BSZ   16
#define NTOK  740
#define NTMP  256
#define NTGT  484
#define DIMC  768
#define NHEAD 12
#define HDIM  64
#define MROWS (BSZ*NTOK)      // 11840
#define SMAX  16.0f           // fixed softmax max (scores bounded ~|6|)

__device__ __forceinline__ float bf2f(u16 u) {
    return __uint_as_float(((unsigned int)u) << 16);
}
__device__ __forceinline__ float bflo(unsigned int u) {
    return __uint_as_float(u << 16);
}
__device__ __forceinline__ float bfhi(unsigned int u) {
    return __uint_as_float(u & 0xffff0000u);
}
__device__ __forceinline__ u16 f2bf(float f) {
    unsigned int u = __float_as_uint(f);
    u += 0x7fffu + ((u >> 16) & 1u);   // RNE
    return (u16)(u >> 16);
}

// async 16B global -> LDS (gfx950). LDS dest must be wave base + lane*16.
__device__ __forceinline__ void gl_lds16(const u16* g, u16* l) {
    __builtin_amdgcn_global_load_lds(
        (const __attribute__((address_space(1))) unsigned int*)(unsigned long long)g,
        (__attribute__((address_space(3))) unsigned int*)(unsigned int)(unsigned long long)l,
        16, 0, 0);
}

// repacked bias offset: [h][i][jb][ln][nt]
__device__ __forceinline__ size_t b2off(int h, int i, int j) {
    return ((size_t)(h * NTOK + i)) * 768 + ((j >> 6) << 6) + ((j & 15) << 2) + ((j >> 4) & 3);
}

// ---------------------------------------------------------------------------
// Fused prep kernel. Block ranges: MLP (long-running, FIRST so it overlaps
// the BW sections instead of tailing) / convert / weight-transpose / bias-diag.
// MLP is 4-way k-split: 484*4 blocks, each thread does 128 of the 512 hidden
// units for one (g,t) token, partials LDS-reduced. All outputs disjoint.
// grid = 1936 + 4440 + 576 + 2220 = 9172.
// ---------------------------------------------------------------------------
#define PREP_MLP  1936
#define PREP_CONV (PREP_MLP + 4440)    // 6376
#define PREP_TRW  (PREP_CONV + 576)    // 6952
#define PREP_ALL  (PREP_TRW + 2220)    // 9172

__global__ __launch_bounds__(256) void prep_kernel(
    const float* __restrict__ x, const float* __restrict__ tq,
    const float* __restrict__ gq, u16* __restrict__ XB, u16* __restrict__ QB,
    const float* __restrict__ w0, const float* __restrict__ w1,
    const float* __restrict__ w2, const float* __restrict__ w3,
    u16* __restrict__ Wt,
    const float* __restrict__ rpb, const float* __restrict__ rpbt,
    const int* __restrict__ tidx, const int* __restrict__ gidx,
    const float* __restrict__ pw1, const float* __restrict__ pb1,
    const float* __restrict__ pw2, const float* __restrict__ pb2,
    const float* __restrict__ tab, u16* __restrict__ bias)
{
    __shared__ float T[64][65];
    const int blk = blockIdx.x;
    const int tid = threadIdx.x;

    if (blk < PREP_MLP) {
        // ----- cross-bias MLP, 4-way k-split -----
        int g  = blk >> 2;                 // 0..483
        int qt = blk & 3;                  // token quarter
        int tl = tid & 63, ks = tid >> 6;  // token-local, k-split 0..3
        int t  = (qt << 6) + tl;           // 0..255
        float a  = tab[(g * NTMP + t) * 2 + 0];
        float bb = tab[(g * NTMP + t) * 2 + 1];
        float acc[NHEAD];
        #pragma unroll
        for (int h = 0; h < NHEAD; h++) acc[h] = 0.0f;
        int k0 = ks << 7;
        #pragma unroll 4
        for (int k = k0; k < k0 + 128; k++) {
            float hid = fmaxf(a * pw1[k] + bb * pw1[512 + k] + pb1[k], 0.0f);
            #pragma unroll
            for (int h = 0; h < NHEAD; h++) acc[h] += hid * pw2[k * NHEAD + h];
        }
        float* R = &T[0][0];               // [ks(4)][tl(64)][h(12)] = 3072 floats
        #pragma unroll
        for (int h = 0; h < NHEAD; h++) R[(ks * 64 + tl) * 12 + h] = acc[h];
        __syncthreads();
        if (ks == 0) {
            #pragma unroll
            for (int h = 0; h < NHEAD; h++) {
                float v = pb2[h] + R[tl * 12 + h] + R[(64 + tl) * 12 + h]
                        + R[(128 + tl) * 12 + h] + R[(192 + tl) * 12 + h];
                u16 u = f2bf(v);
                bias[b2off(h, t, NTMP + g)] = u;   // top-right
                bias[b2off(h, NTMP + g, t)] = u;   // bottom-left
            }
        }
    } else if (blk < PREP_CONV) {
        // ----- fp32 -> bf16 convert: XB, QB -----
        int c = (blk - PREP_MLP) * 256 + tid;
        {
            const float* s = x + (size_t)c * 8;
            float4 p0 = *(const float4*)s, p1 = *(const float4*)(s + 4);
            u16 e[8] = {f2bf(p0.x), f2bf(p0.y), f2bf(p0.z), f2bf(p0.w),
                        f2bf(p1.x), f2bf(p1.y), f2bf(p1.z), f2bf(p1.w)};
            *(uint4*)(XB + (size_t)c * 8) = *(uint4*)e;
        }
        {
            int row = c / 96, cc = (c - row * 96) * 8;
            int b = row / NTOK, n = row - b * NTOK;
            const float* s = (n < NTMP)
                           ? tq + ((size_t)(b * NTMP + n)) * DIMC + cc
                           : gq + ((size_t)(b * NTGT + (n - NTMP))) * DIMC + cc;
            float4 p0 = *(const float4*)s, p1 = *(const float4*)(s + 4);
            u16 e[8] = {f2bf(p0.x), f2bf(p0.y), f2bf(p0.z), f2bf(p0.w),
                        f2bf(p1.x), f2bf(p1.y), f2bf(p1.z), f2bf(p1.w)};
            *(uint4*)(QB + (size_t)row * DIMC + cc) = *(uint4*)e;
        }
    } else if (blk < PREP_TRW) {
        // ----- weight transpose + bf16 (z=0 scaled 1/8) -----
        int t = blk - PREP_CONV;          // 0..575
        int z = t / 144, rem = t - z * 144;
        int bx = rem % 12, by = rem / 12;
        const float* src = (z == 0) ? w0 : (z == 1) ? w1 : (z == 2) ? w2 : w3;
        const float scale = (z == 0) ? 0.125f : 1.0f;
        u16* dst = Wt + (size_t)z * DIMC * DIMC;
        int out0 = bx * 64, in0 = by * 64;
        #pragma unroll
        for (int l = 0; l < 4; l++) {
            int u = tid + (l << 8);
            int r = u >> 4, c4 = (u & 15) << 2;
            float4 p = *(const float4*)(src + (size_t)(in0 + r) * DIMC + out0 + c4);
            T[r][c4] = p.x; T[r][c4 + 1] = p.y; T[r][c4 + 2] = p.z; T[r][c4 + 3] = p.w;
        }
        __syncthreads();
        #pragma unroll
        for (int l = 0; l < 2; l++) {
            int u = tid + (l << 8);
            int r = u >> 3, c8 = (u & 7) << 3;
            u16 e[8];
            #pragma unroll
            for (int i = 0; i < 8; i++) e[i] = f2bf(T[c8 + i][r] * scale);
            *(uint4*)(dst + (size_t)(out0 + r) * DIMC + in0 + c8) = *(uint4*)e;
        }
    } else {
        // ----- bias diagonal blocks + padding -----
        int t = blk - PREP_TRW;           // 0..2219
        int jb = t % 3, i = t / 3;
        int j = jb * 256 + tid;
        u16 vals[NHEAD];
        if (j >= NTOK) {
            u16 neg = f2bf(-1e30f);
            #pragma unroll
            for (int h = 0; h < NHEAD; h++) vals[h] = neg;
        } else if (i < NTMP && j < NTMP) {
            int idx = tidx[i * NTMP + j];
            #pragma unroll
            for (int h = 0; h < NHEAD; h++) vals[h] = f2bf(rpbt[idx * NHEAD + h]);
        } else if (i >= NTMP && j >= NTMP) {
            int idx = gidx[(i - NTMP) * NTGT + (j - NTMP)];
            #pragma unroll
            for (int h = 0; h < NHEAD; h++) vals[h] = f2bf(rpb[idx * NHEAD + h]);
        } else {
            return;  // cross region
        }
        #pragma unroll
        for (int h = 0; h < NHEAD; h++) bias[b2off(h, i, j)] = vals[h];
    }
}

// ---------------------------------------------------------------------------
// bf16 MFMA GEMM, BM=BN=128, BK=64, chunk-major LDS, gl_lds w16.
// 2-phase double-buffered K-loop; bijective XCD-chunked blockIdx swizzle.
// MODE 0: out bf16 -> C0. MODE 1: KV (bx<6 -> K, else V). MODE 2: fp32+pb.
// NOTE: MODE 0 (reads QB) and MODE 1 (writes V==QB) MUST be separate launches.
// ---------------------------------------------------------------------------
template<int MODE>
__global__ __launch_bounds__(256) void gemm_bf16(
    const u16* __restrict__ A, const u16* __restrict__ Wt,
    const float* __restrict__ pb, u16* __restrict__ C0,
    u16* __restrict__ C1, float* __restrict__ Cf)
{
    __shared__ __align__(16) u16 As[2][8192];   // [buf][chunk(8)][row(128)][8]
    __shared__ __align__(16) u16 Bs[2][8192];
    const int tid = threadIdx.x;
    const int lane = tid & 63, w = tid >> 6;
    const int quad = lane >> 4, ln = lane & 15;

    // XCD-chunked bijective swizzle (hw dispatch id -> logical wg).
    const int gx = gridDim.x;
    const int nwg = gx * (int)gridDim.y;
    const int flat = blockIdx.y * gx + blockIdx.x;
    const int q = nwg >> 3, r = nwg & 7;
    const int xcd = flat & 7, sidx = flat >> 3;
    const int wg = (xcd < r) ? xcd * (q + 1) + sidx
                             : r * (q + 1) + (xcd - r) * q + sidx;
    const int by = wg / gx, bx = wg - by * gx;

    const int m0 = by << 7;
    const int wm = (w >> 1) << 6, wn = (w & 1) << 6;

    const int nn = bx << 7;
    const u16* Wbase = Wt + (size_t)nn * DIMC;
    u16* Cb;
    int col0;
    if (MODE == 1) {
        if (nn < DIMC) { col0 = nn; Cb = C0; }
        else           { col0 = nn - DIMC; Cb = C1; }
    } else {
        col0 = nn; Cb = C0;
    }

    f32x4 acc[4][4];
    #pragma unroll
    for (int i = 0; i < 4; i++)
        #pragma unroll
        for (int j = 0; j < 4; j++)
            acc[i][j] = (f32x4){0.f, 0.f, 0.f, 0.f};

#define STAGE(s, k0) do {                                                     \
    _Pragma("unroll")                                                         \
    for (int l = 0; l < 4; l++) {                                             \
        int f = tid + (l << 8);          /* 0..1023 */                        \
        int c8 = f >> 7, rr = f & 127;                                        \
        int grow = m0 + rr; if (grow >= MROWS) grow = MROWS - 1;              \
        gl_lds16(A + (size_t)grow * DIMC + (k0) + c8 * 8, &As[s][f * 8]);     \
        gl_lds16(Wbase + (size_t)rr * DIMC + (k0) + c8 * 8, &Bs[s][f * 8]);   \
    } } while (0)

#define COMPUTE(s) do {                                                       \
    _Pragma("unroll")                                                         \
    for (int kp = 0; kp < 2; kp++) {                                          \
        bf16x8 af[4], bfr[4];                                                 \
        _Pragma("unroll")                                                     \
        for (int mt = 0; mt < 4; mt++)                                        \
            af[mt] = *(const bf16x8*)                                         \
                &As[s][(((kp << 2) + quad) * 128 + wm + mt * 16 + ln) * 8];   \
        _Pragma("unroll")                                                     \
        for (int nt = 0; nt < 4; nt++)                                        \
            bfr[nt] = *(const bf16x8*)                                        \
                &Bs[s][(((kp << 2) + quad) * 128 + wn + nt * 16 + ln) * 8];   \
        _Pragma("unroll")                                                     \
        for (int mt = 0; mt < 4; mt++)                                        \
            _Pragma("unroll")                                                 \
            for (int nt = 0; nt < 4; nt++)                                    \
                acc[mt][nt] = __builtin_amdgcn_mfma_f32_16x16x32_bf16(        \
                    af[mt], bfr[nt], acc[mt][nt], 0, 0, 0);                   \
    } } while (0)

    // prologue: stage tile 0, drain, then 2-phase pipeline over 12 K-tiles
    STAGE(0, 0);
    __syncthreads();
    #pragma unroll 1
    for (int t = 0; t < 12; t += 2) {
        STAGE(1, (t + 1) << 6);          // t<=10 so t+1<=11: always valid
        COMPUTE(0);
        __syncthreads();                 // drains vmcnt(0): tile t+1 ready
        if (t < 10) STAGE(0, (t + 2) << 6);
        COMPUTE(1);
        __syncthreads();
    }

#undef STAGE
#undef COMPUTE

    #pragma unroll
    for (int mt = 0; mt < 4; mt++) {
        #pragma unroll
        for (int reg = 0; reg < 4; reg++) {
            int grow = m0 + wm + mt * 16 + (quad << 2) + reg;
            if (grow >= MROWS) continue;
            #pragma unroll
            for (int nt = 0; nt < 4; nt++) {
                int gcol = col0 + wn + nt * 16 + ln;
                float v = acc[mt][nt][reg];
                if (MODE == 2) {
                    Cf[(size_t)grow * DIMC + gcol] = v + pb[gcol];
                } else {
                    Cb[(size_t)grow * DIMC + gcol] = f2bf(v);
                }
            }
        }
    }
}

// ---------------------------------------------------------------------------
// Flash MFMA attention, fixed-max softmax, 2-phase double-buffered j-loop.
// 128 Q-rows/block; each wave owns two 16-row m-frags. K via gl_lds into
// double-buffered chunk-major LDS; V parked in registers (issue-early) and
// written transposed into double-buffered XOR-swizzled stride-72 LDS
// (write-late, T14); bias double-buffered in registers. Compute on tile t
// overlaps the in-flight loads of tile t+1; the vmcnt(0) drain at the
// post-compute barrier is then cheap. grid (6, 12, 16).
// ---------------------------------------------------------------------------
__global__ __launch_bounds__(256) void attn_mfma(
    const u16* __restrict__ Qg, const u16* __restrict__ Kg,
    const u16* __restrict__ Vg, const u16* __restrict__ bias,
    u16* __restrict__ ctx)
{
    __shared__ __align__(16) u16 KsL[2][4096];     // [buf][chunk(8)][jr(64)][8]
    __shared__ __align__(16) u16 VtL[2][64 * 72];  // [buf][d][j^swz], stride 72
    __shared__ __align__(16) u16 Pw[8][16][72];    // [w*2+mi][m][k^swz]

    const int tid = threadIdx.x;
    const int lane = tid & 63, w = tid >> 6;
    const int quad = lane >> 4, ln = lane & 15;
    const int b = blockIdx.z, h = blockIdx.y;
    const int q0 = blockIdx.x << 7;
    const int mbase = q0 + (w << 5);               // wave's 32 rows
    const u16* bp = bias + ((size_t)h * NTOK) * 768;

    // Q fragments for both m-frags (A-layout), held for the whole kernel
    bf16x8 aq[2][2];
    #pragma unroll
    for (int mi = 0; mi < 2; mi++) {
        int qrow = mbase + (mi << 4) + ln; if (qrow >= NTOK) qrow = NTOK - 1;
        #pragma unroll
        for (int kp = 0; kp < 2; kp++)
            aq[mi][kp] = *(const bf16x8*)(Qg + ((size_t)(b * NTOK + qrow)) * DIMC
                                          + h * HDIM + kp * 32 + (quad << 3));
    }
    int boff[2][4];
    #pragma unroll
    for (int mi = 0; mi < 2; mi++)
        #pragma unroll
        for (int reg = 0; reg < 4; reg++) {
            int rr = mbase + (mi << 4) + (quad << 2) + reg;
            if (rr >= NTOK) rr = NTOK - 1;
            boff[mi][reg] = rr * 768 + (ln << 2);
        }

    // V staging geometry (per thread, fixed)
    int vjr[2], vd0[2];
    #pragma unroll
    for (int l = 0; l < 2; l++) {
        int u = tid + (l << 8);
        vjr[l] = u >> 3; vd0[l] = (u & 7) << 3;
    }

    // P read swizzle constant (row = ln)
    const int pswz = ((ln >> 2) & 3) << 4;

    float rs[2][4] = {};
    f32x4 O[2][4];
    #pragma unroll
    for (int mi = 0; mi < 2; mi++)
        #pragma unroll
        for (int dt = 0; dt < 4; dt++) O[mi][dt] = (f32x4){0.f, 0.f, 0.f, 0.f};

    uint4 vp[2];
    uint2 bvv[2][4], bvn[2][4];

#define STAGE_K(j0, s) do {                                                   \
    _Pragma("unroll")                                                         \
    for (int l = 0; l < 2; l++) {                                             \
        int f = tid + (l << 8);                                               \
        int chunk = f >> 6, jr = f & 63;                                      \
        int krow = (j0) + jr; if (krow >= NTOK) krow = NTOK - 1;              \
        gl_lds16(Kg + ((size_t)(b * NTOK + krow)) * DIMC + h * HDIM + chunk * 8, \
                 &KsL[s][f * 8]);                                             \
    } } while (0)

#define LOAD_V(j0) do {                                                       \
    _Pragma("unroll")                                                         \
    for (int l = 0; l < 2; l++) {                                             \
        int vrow = (j0) + vjr[l]; if (vrow >= NTOK) vrow = NTOK - 1;          \
        vp[l] = *(const uint4*)(Vg + ((size_t)(b * NTOK + vrow)) * DIMC        \
                                + h * HDIM + vd0[l]);                         \
    } } while (0)

#define WRITE_V(s) do {                                                       \
    _Pragma("unroll")                                                         \
    for (int l = 0; l < 2; l++) {                                             \
        const u16* pe = (const u16*)&vp[l];                                   \
        int jswz = vjr[l] ^ vd0[l];                                           \
        _Pragma("unroll")                                                     \
        for (int i = 0; i < 8; i++)                                           \
            VtL[s][(vd0[l] + i) * 72 + jswz] = pe[i];                         \
    } } while (0)

#define LOAD_B(j0, dst) do {                                                  \
    _Pragma("unroll")                                                         \
    for (int mi = 0; mi < 2; mi++)                                            \
        _Pragma("unroll")                                                     \
        for (int reg = 0; reg < 4; reg++)                                     \
            dst[mi][reg] = *(const uint2*)(bp + boff[mi][reg] + (j0));        \
    } while (0)

    // prologue: tile 0
    STAGE_K(0, 0);
    LOAD_V(0);
    LOAD_B(0, bvv);
    __syncthreads();        // drain K[0] gl_lds + vp loads
    WRITE_V(0);
    __syncthreads();

    for (int tt = 0; tt < 12; tt++) {
        const int p = tt & 1;
        const int j0n = (tt + 1) << 6;
        if (tt < 11) {
            STAGE_K(j0n, p ^ 1);     // safe: Ks[p^1] readers finished at tt-1
            LOAD_V(j0n);
            LOAD_B(j0n, bvn);
        }

        // V B-frags (shared by both m-frags), b128 via swizzled offset
        bf16x8 bv[4][2];
        #pragma unroll
        for (int dt = 0; dt < 4; dt++) {
            int key8 = ((dt * 2 + (ln >> 3)) & 7) << 3;
            #pragma unroll
            for (int kp = 0; kp < 2; kp++) {
                int koff = (kp * 32 + (quad << 3)) ^ key8;
                bv[dt][kp] = *(const bf16x8*)&VtL[p][(dt * 16 + ln) * 72 + koff];
            }
        }

        // S = (Q/8) K^T, K-frags read once, both m-frags interleaved
        f32x4 s[2][4];
        #pragma unroll
        for (int mi = 0; mi < 2; mi++)
            #pragma unroll
            for (int nt = 0; nt < 4; nt++) s[mi][nt] = (f32x4){0.f, 0.f, 0.f, 0.f};
        __builtin_amdgcn_s_setprio(1);
        #pragma unroll
        for (int kp = 0; kp < 2; kp++)
            #pragma unroll
            for (int nt = 0; nt < 4; nt++) {
                bf16x8 bk = *(const bf16x8*)
                    &KsL[p][(((kp << 2) + quad) * 64 + nt * 16 + ln) * 8];
                s[0][nt] = __builtin_amdgcn_mfma_f32_16x16x32_bf16(aq[0][kp], bk, s[0][nt], 0, 0, 0);
                s[1][nt] = __builtin_amdgcn_mfma_f32_16x16x32_bf16(aq[1][kp], bk, s[1][nt], 0, 0, 0);
            }
        __builtin_amdgcn_s_setprio(0);

        #pragma unroll
        for (int mi = 0; mi < 2; mi++) {
            // + bias, exp(s - SMAX), accumulate row sums
            #pragma unroll
            for (int reg = 0; reg < 4; reg++) {
                uint2 bb = bvv[mi][reg];
                float p0 = __expf(s[mi][0][reg] + bflo(bb.x) - SMAX);
                float p1 = __expf(s[mi][1][reg] + bfhi(bb.x) - SMAX);
                float p2 = __expf(s[mi][2][reg] + bflo(bb.y) - SMAX);
                float p3 = __expf(s[mi][3][reg] + bfhi(bb.y) - SMAX);
                s[mi][0][reg] = p0; s[mi][1][reg] = p1;
                s[mi][2][reg] = p2; s[mi][3][reg] = p3;
                rs[mi][reg] += p0 + p1 + p2 + p3;
            }
            // P: C-layout -> A-layout through swizzled wave-private LDS:
            // write row quad*4+reg, col (nt^quad)*16 + ln
            u16* pwb = &Pw[(w << 1) + mi][0][0];
            #pragma unroll
            for (int nt = 0; nt < 4; nt++) {
                int colw = ((nt ^ quad) << 4) + ln;
                #pragma unroll
                for (int reg = 0; reg < 4; reg++)
                    pwb[((quad << 2) + reg) * 72 + colw] = f2bf(s[mi][nt][reg]);
            }
            bf16x8 ap[2];
            #pragma unroll
            for (int kp = 0; kp < 2; kp++) {
                int koff = (kp * 32 + (quad << 3)) ^ pswz;
                ap[kp] = *(const bf16x8*)&pwb[ln * 72 + koff];
            }
            // O += P V
            __builtin_amdgcn_s_setprio(1);
            #pragma unroll
            for (int dt = 0; dt < 4; dt++)
                #pragma unroll
                for (int kp = 0; kp < 2; kp++)
                    O[mi][dt] = __builtin_amdgcn_mfma_f32_16x16x32_bf16(
                        ap[kp], bv[dt][kp], O[mi][dt], 0, 0, 0);
            __builtin_amdgcn_s_setprio(0);
        }

        __syncthreads();    // all waves done reading Ks[p]/Vt[p]; drains
                            // vmcnt(0) -> Ks[p^1] landed, vp/bvn loaded
        if (tt < 11) {
            WRITE_V(p ^ 1);
            #pragma unroll
            for (int mi = 0; mi < 2; mi++)
                #pragma unroll
                for (int reg = 0; reg < 4; reg++)
                    bvv[mi][reg] = bvn[mi][reg];
            __syncthreads();    // Vt[p^1] writes visible
        }
    }

#undef STAGE_K
#undef LOAD_V
#undef WRITE_V
#undef LOAD_B

    // normalize + store
    #pragma unroll
    for (int mi = 0; mi < 2; mi++) {
        #pragma unroll
        for (int reg = 0; reg < 4; reg++) {
            float t = rs[mi][reg];
            #pragma unroll
            for (int mk = 8; mk >= 1; mk >>= 1) t += __shfl_xor(t, mk);
            float inv = 1.0f / t;
            int row = mbase + (mi << 4) + (quad << 2) + reg;
            if (row < NTOK) {
                #pragma unroll
                for (int dt = 0; dt < 4; dt++)
                    ctx[((size_t)(b * NTOK + row)) * DIMC + h * HDIM + dt * 16 + ln]
                        = f2bf(O[mi][dt][reg] * inv);
            }
        }
    }
}

// ---------------------------------------------------------------------------
extern "C" void kernel_launch(void* const* d_in, const int* in_sizes, int n_in,
                              void* d_out, int out_size, void* d_ws, size_t ws_size,
                              hipStream_t stream)
{
    const float* x        = (const float*)d_in[0];
    const float* temp_q   = (const float*)d_in[1];
    const float* target_q = (const float*)d_in[2];
    const float* q_w      = (const float*)d_in[3];
    const float* k_w      = (const float*)d_in[4];
    const float* v_w      = (const float*)d_in[5];
    const float* proj_w   = (const float*)d_in[6];
    const float* proj_b   = (const float*)d_in[7];
    const float* rpb      = (const float*)d_in[8];
    const float* rpbt     = (const float*)d_in[9];
    const float* pw1      = (const float*)d_in[10];
    const float* pb1      = (const float*)d_in[11];
    const float* pw2      = (const float*)d_in[12];
    const float* pb2      = (const float*)d_in[13];
    const float* tab      = (const float*)d_in[14];
    const int*   tidx     = (const int*)d_in[15];
    const int*   gidx     = (const int*)d_in[16];
    float* out = (float*)d_out;

    char* ws = (char*)d_ws;
    const size_t S = (size_t)MROWS * DIMC * sizeof(u16);          // 18,186,240
    const size_t SZB = (size_t)NHEAD * NTOK * 768 * sizeof(u16);  // 13,639,680
    u16* XB    = (u16*)(ws);           // also CTX (aliased, after KV gemm)
    u16* QB    = (u16*)(ws + S);       // also V (aliased, after Q gemm)
    u16* Q     = (u16*)(ws + 2 * S);
    u16* K     = (u16*)(ws + 3 * S);
    u16* V     = QB;
    u16* CTX   = XB;
    u16* BIAS2 = (u16*)(ws + 4 * S);
    u16* WT    = (u16*)(ws + 4 * S + SZB);                        // 4 x 768 x 768

    prep_kernel<<<dim3(PREP_ALL), 256, 0, stream>>>(
        x, temp_q, target_q, XB, QB,
        q_w, k_w, v_w, proj_w, WT,
        rpb, rpbt, tidx, gidx,
        pw1, pb1, pw2, pb2, tab, BIAS2);

    const u16* WTq = WT;
    const u16* WTk = WT + (size_t)DIMC * DIMC;    // k plane (v plane adjacent)
    const u16* WTp = WT + 3 * (size_t)DIMC * DIMC;

    gemm_bf16<0><<<dim3(6, 93), 256, 0, stream>>>(QB, WTq, nullptr, Q, nullptr, nullptr);
    gemm_bf16<1><<<dim3(12, 93), 256, 0, stream>>>(XB, WTk, nullptr, K, V, nullptr);
    attn_mfma<<<dim3(6, 12, 16), 256, 0, stream>>>(Q, K, V, BIAS2, CTX);
    gemm_bf16<2><<<dim3(6, 93), 256, 0, stream>>>(CTX, WTp, proj_b, nullptr, nullptr, out);
}

// Round 4
// 464.961 us; speedup vs baseline: 1.1858x; 1.1858x over previous
//
#include <hip/hip_runtime.h>

// Convattn: B=16, N=740 (256+484), C=768, H=12, hd=64. Inputs/outputs fp32.
// ws: XB/QB/Q/K/V/CTX bf16 (V aliases QB — safe ONLY because Q-GEMM and
// KV-GEMM are separate ordered launches; do NOT fuse them), BIAS2 bf16
// repacked [h][row][jb][ln][nt], WT bf16 (q-plane pre-scaled 0.125).

typedef unsigned short u16;
typedef short bf16x8 __attribute__((ext_vector_type(8)));
typedef float f32x4 __attribute__((ext_vector_type(4)));

#define BSZ   16
#define NTOK  740
#define NTMP  256
#define NTGT  484
#define DIMC  768
#define NHEAD 12
#define HDIM  64
#define MROWS (BSZ*NTOK)      // 11840
#define SMAX  16.0f           // fixed softmax max (scores bounded ~|6|)

__device__ __forceinline__ float bf2f(u16 u) {
    return __uint_as_float(((unsigned int)u) << 16);
}
__device__ __forceinline__ float bflo(unsigned int u) {
    return __uint_as_float(u << 16);
}
__device__ __forceinline__ float bfhi(unsigned int u) {
    return __uint_as_float(u & 0xffff0000u);
}
__device__ __forceinline__ u16 f2bf(float f) {
    unsigned int u = __float_as_uint(f);
    u += 0x7fffu + ((u >> 16) & 1u);   // RNE
    return (u16)(u >> 16);
}

// async 16B global -> LDS (gfx950). LDS dest must be wave base + lane*16.
__device__ __forceinline__ void gl_lds16(const u16* g, u16* l) {
    __builtin_amdgcn_global_load_lds(
        (const __attribute__((address_space(1))) unsigned int*)(unsigned long long)g,
        (__attribute__((address_space(3))) unsigned int*)(unsigned int)(unsigned long long)l,
        16, 0, 0);
}

// repacked bias offset: [h][i][jb][ln][nt]
__device__ __forceinline__ size_t b2off(int h, int i, int j) {
    return ((size_t)(h * NTOK + i)) * 768 + ((j >> 6) << 6) + ((j & 15) << 2) + ((j >> 4) & 3);
}

// ---------------------------------------------------------------------------
// Fused prep kernel: block ranges do MLP (FIRST: long serial blocks overlap
// the BW sections instead of tailing) / convert / weight-transpose /
// bias-diag. Bodies identical to the proven R1 versions (keep codegen:
// VGPR 16 / SGPR 96 s_load batching in the MLP loop).
// grid = 484 + 4440 + 576 + 2220 = 7720.
// ---------------------------------------------------------------------------
#define PREP_MLP  484
#define PREP_CONV (PREP_MLP + 4440)    // 4924
#define PREP_TRW  (PREP_CONV + 576)    // 5500
#define PREP_ALL  (PREP_TRW + 2220)    // 7720

__global__ __launch_bounds__(256) void prep_kernel(
    const float* __restrict__ x, const float* __restrict__ tq,
    const float* __restrict__ gq, u16* __restrict__ XB, u16* __restrict__ QB,
    const float* __restrict__ w0, const float* __restrict__ w1,
    const float* __restrict__ w2, const float* __restrict__ w3,
    u16* __restrict__ Wt,
    const float* __restrict__ rpb, const float* __restrict__ rpbt,
    const int* __restrict__ tidx, const int* __restrict__ gidx,
    const float* __restrict__ pw1, const float* __restrict__ pb1,
    const float* __restrict__ pw2, const float* __restrict__ pb2,
    const float* __restrict__ tab, u16* __restrict__ bias)
{
    __shared__ float T[64][65];
    const int blk = blockIdx.x;
    const int tid = threadIdx.x;

    if (blk < PREP_MLP) {
        // ----- cross-bias MLP (R1 body verbatim) -----
        int g = blk;                      // 0..483
        int t = tid;                      // 0..255
        float a  = tab[(g * NTMP + t) * 2 + 0];
        float bb = tab[(g * NTMP + t) * 2 + 1];
        float acc[NHEAD];
        #pragma unroll
        for (int h = 0; h < NHEAD; h++) acc[h] = pb2[h];
        for (int k = 0; k < 512; k++) {
            float hid = fmaxf(a * pw1[k] + bb * pw1[512 + k] + pb1[k], 0.0f);
            #pragma unroll
            for (int h = 0; h < NHEAD; h++) acc[h] += hid * pw2[k * NHEAD + h];
        }
        #pragma unroll
        for (int h = 0; h < NHEAD; h++) {
            u16 v = f2bf(acc[h]);
            bias[b2off(h, t, NTMP + g)] = v;   // top-right
            bias[b2off(h, NTMP + g, t)] = v;   // bottom-left
        }
    } else if (blk < PREP_CONV) {
        // ----- fp32 -> bf16 convert: XB, QB -----
        int c = (blk - PREP_MLP) * 256 + tid;
        {
            const float* s = x + (size_t)c * 8;
            float4 p0 = *(const float4*)s, p1 = *(const float4*)(s + 4);
            u16 e[8] = {f2bf(p0.x), f2bf(p0.y), f2bf(p0.z), f2bf(p0.w),
                        f2bf(p1.x), f2bf(p1.y), f2bf(p1.z), f2bf(p1.w)};
            *(uint4*)(XB + (size_t)c * 8) = *(uint4*)e;
        }
        {
            int row = c / 96, cc = (c - row * 96) * 8;
            int b = row / NTOK, n = row - b * NTOK;
            const float* s = (n < NTMP)
                           ? tq + ((size_t)(b * NTMP + n)) * DIMC + cc
                           : gq + ((size_t)(b * NTGT + (n - NTMP))) * DIMC + cc;
            float4 p0 = *(const float4*)s, p1 = *(const float4*)(s + 4);
            u16 e[8] = {f2bf(p0.x), f2bf(p0.y), f2bf(p0.z), f2bf(p0.w),
                        f2bf(p1.x), f2bf(p1.y), f2bf(p1.z), f2bf(p1.w)};
            *(uint4*)(QB + (size_t)row * DIMC + cc) = *(uint4*)e;
        }
    } else if (blk < PREP_TRW) {
        // ----- weight transpose + bf16 (z=0 scaled 1/8) -----
        int t = blk - PREP_CONV;          // 0..575
        int z = t / 144, rem = t - z * 144;
        int bx = rem % 12, by = rem / 12;
        const float* src = (z == 0) ? w0 : (z == 1) ? w1 : (z == 2) ? w2 : w3;
        const float scale = (z == 0) ? 0.125f : 1.0f;
        u16* dst = Wt + (size_t)z * DIMC * DIMC;
        int out0 = bx * 64, in0 = by * 64;
        #pragma unroll
        for (int l = 0; l < 4; l++) {
            int u = tid + (l << 8);
            int r = u >> 4, c4 = (u & 15) << 2;
            float4 p = *(const float4*)(src + (size_t)(in0 + r) * DIMC + out0 + c4);
            T[r][c4] = p.x; T[r][c4 + 1] = p.y; T[r][c4 + 2] = p.z; T[r][c4 + 3] = p.w;
        }
        __syncthreads();
        #pragma unroll
        for (int l = 0; l < 2; l++) {
            int u = tid + (l << 8);
            int r = u >> 3, c8 = (u & 7) << 3;
            u16 e[8];
            #pragma unroll
            for (int i = 0; i < 8; i++) e[i] = f2bf(T[c8 + i][r] * scale);
            *(uint4*)(dst + (size_t)(out0 + r) * DIMC + in0 + c8) = *(uint4*)e;
        }
    } else {
        // ----- bias diagonal blocks + padding -----
        int t = blk - PREP_TRW;           // 0..2219
        int jb = t % 3, i = t / 3;
        int j = jb * 256 + tid;
        u16 vals[NHEAD];
        if (j >= NTOK) {
            u16 neg = f2bf(-1e30f);
            #pragma unroll
            for (int h = 0; h < NHEAD; h++) vals[h] = neg;
        } else if (i < NTMP && j < NTMP) {
            int idx = tidx[i * NTMP + j];
            #pragma unroll
            for (int h = 0; h < NHEAD; h++) vals[h] = f2bf(rpbt[idx * NHEAD + h]);
        } else if (i >= NTMP && j >= NTMP) {
            int idx = gidx[(i - NTMP) * NTGT + (j - NTMP)];
            #pragma unroll
            for (int h = 0; h < NHEAD; h++) vals[h] = f2bf(rpb[idx * NHEAD + h]);
        } else {
            return;  // cross region
        }
        #pragma unroll
        for (int h = 0; h < NHEAD; h++) bias[b2off(h, i, j)] = vals[h];
    }
}

// ---------------------------------------------------------------------------
// bf16 MFMA GEMM, BM=BN=128, BK=64, chunk-major LDS, gl_lds w16.
// 2-phase double-buffered K-loop; bijective XCD-chunked blockIdx swizzle.
// MODE 0: out bf16 -> C0. MODE 1: KV (bx<6 -> K, else V). MODE 2: fp32+pb.
// NOTE: MODE 0 (reads QB) and MODE 1 (writes V==QB) MUST be separate launches.
// ---------------------------------------------------------------------------
template<int MODE>
__global__ __launch_bounds__(256) void gemm_bf16(
    const u16* __restrict__ A, const u16* __restrict__ Wt,
    const float* __restrict__ pb, u16* __restrict__ C0,
    u16* __restrict__ C1, float* __restrict__ Cf)
{
    __shared__ __align__(16) u16 As[2][8192];   // [buf][chunk(8)][row(128)][8]
    __shared__ __align__(16) u16 Bs[2][8192];
    const int tid = threadIdx.x;
    const int lane = tid & 63, w = tid >> 6;
    const int quad = lane >> 4, ln = lane & 15;

    // XCD-chunked bijective swizzle (hw dispatch id -> logical wg).
    const int gx = gridDim.x;
    const int nwg = gx * (int)gridDim.y;
    const int flat = blockIdx.y * gx + blockIdx.x;
    const int q = nwg >> 3, r = nwg & 7;
    const int xcd = flat & 7, sidx = flat >> 3;
    const int wg = (xcd < r) ? xcd * (q + 1) + sidx
                             : r * (q + 1) + (xcd - r) * q + sidx;
    const int by = wg / gx, bx = wg - by * gx;

    const int m0 = by << 7;
    const int wm = (w >> 1) << 6, wn = (w & 1) << 6;

    const int nn = bx << 7;
    const u16* Wbase = Wt + (size_t)nn * DIMC;
    u16* Cb;
    int col0;
    if (MODE == 1) {
        if (nn < DIMC) { col0 = nn; Cb = C0; }
        else           { col0 = nn - DIMC; Cb = C1; }
    } else {
        col0 = nn; Cb = C0;
    }

    f32x4 acc[4][4];
    #pragma unroll
    for (int i = 0; i < 4; i++)
        #pragma unroll
        for (int j = 0; j < 4; j++)
            acc[i][j] = (f32x4){0.f, 0.f, 0.f, 0.f};

#define STAGE(s, k0) do {                                                     \
    _Pragma("unroll")                                                         \
    for (int l = 0; l < 4; l++) {                                             \
        int f = tid + (l << 8);          /* 0..1023 */                        \
        int c8 = f >> 7, rr = f & 127;                                        \
        int grow = m0 + rr; if (grow >= MROWS) grow = MROWS - 1;              \
        gl_lds16(A + (size_t)grow * DIMC + (k0) + c8 * 8, &As[s][f * 8]);     \
        gl_lds16(Wbase + (size_t)rr * DIMC + (k0) + c8 * 8, &Bs[s][f * 8]);   \
    } } while (0)

#define COMPUTE(s) do {                                                       \
    _Pragma("unroll")                                                         \
    for (int kp = 0; kp < 2; kp++) {                                          \
        bf16x8 af[4], bfr[4];                                                 \
        _Pragma("unroll")                                                     \
        for (int mt = 0; mt < 4; mt++)                                        \
            af[mt] = *(const bf16x8*)                                         \
                &As[s][(((kp << 2) + quad) * 128 + wm + mt * 16 + ln) * 8];   \
        _Pragma("unroll")                                                     \
        for (int nt = 0; nt < 4; nt++)                                        \
            bfr[nt] = *(const bf16x8*)                                        \
                &Bs[s][(((kp << 2) + quad) * 128 + wn + nt * 16 + ln) * 8];   \
        _Pragma("unroll")                                                     \
        for (int mt = 0; mt < 4; mt++)                                        \
            _Pragma("unroll")                                                 \
            for (int nt = 0; nt < 4; nt++)                                    \
                acc[mt][nt] = __builtin_amdgcn_mfma_f32_16x16x32_bf16(        \
                    af[mt], bfr[nt], acc[mt][nt], 0, 0, 0);                   \
    } } while (0)

    // prologue: stage tile 0, drain, then 2-phase pipeline over 12 K-tiles
    STAGE(0, 0);
    __syncthreads();
    #pragma unroll 1
    for (int t = 0; t < 12; t += 2) {
        STAGE(1, (t + 1) << 6);          // t<=10 so t+1<=11: always valid
        COMPUTE(0);
        __syncthreads();                 // drains vmcnt(0): tile t+1 ready
        if (t < 10) STAGE(0, (t + 2) << 6);
        COMPUTE(1);
        __syncthreads();
    }

#undef STAGE
#undef COMPUTE

    #pragma unroll
    for (int mt = 0; mt < 4; mt++) {
        #pragma unroll
        for (int reg = 0; reg < 4; reg++) {
            int grow = m0 + wm + mt * 16 + (quad << 2) + reg;
            if (grow >= MROWS) continue;
            #pragma unroll
            for (int nt = 0; nt < 4; nt++) {
                int gcol = col0 + wn + nt * 16 + ln;
                float v = acc[mt][nt][reg];
                if (MODE == 2) {
                    Cf[(size_t)grow * DIMC + gcol] = v + pb[gcol];
                } else {
                    Cb[(size_t)grow * DIMC + gcol] = f2bf(v);
                }
            }
        }
    }
}

// ---------------------------------------------------------------------------
// Flash MFMA attention, fixed-max softmax (R1 structure: single-buffered,
// 2 barriers/tile — cross-block TLP at 4 blocks/CU is the latency hider).
// h-major XCD-chunked block remap: 1152 blocks = 8 XCDs x 144; each XCD
// covers ~1.5 heads, so the per-h bias slab (1.06 MB) + K/V stay L2-hot.
// T5 setprio around both MFMA clusters. grid (6, 12, 16).
// ---------------------------------------------------------------------------
__global__ __launch_bounds__(256) void attn_mfma(
    const u16* __restrict__ Qg, const u16* __restrict__ Kg,
    const u16* __restrict__ Vg, const u16* __restrict__ bias,
    u16* __restrict__ ctx)
{
    __shared__ __align__(16) u16 KsL[4096];        // [chunk(8)][jr(64)][8]
    __shared__ __align__(16) u16 VtL[64 * 72];     // [d][j^swz], stride 72
    __shared__ __align__(16) u16 Pw[8][16][72];    // [w*2+mi][m][k^swz]

    const int tid = threadIdx.x;
    const int lane = tid & 63, w = tid >> 6;
    const int quad = lane >> 4, ln = lane & 15;

    // h-major XCD-chunked remap (bijective: 1152 = 8 * 144).
    const int flat = (blockIdx.z * 12 + blockIdx.y) * 6 + blockIdx.x;
    const int wg = (flat & 7) * 144 + (flat >> 3);
    const int h = wg / 96;
    const int rem = wg - h * 96;
    const int b = rem / 6;
    const int q0 = (rem - b * 6) << 7;

    const int mbase = q0 + (w << 5);               // wave's 32 rows
    const u16* bp = bias + ((size_t)h * NTOK) * 768;

    // Q fragments for both m-frags (A-layout), held for the whole kernel
    bf16x8 aq[2][2];
    #pragma unroll
    for (int mi = 0; mi < 2; mi++) {
        int qrow = mbase + (mi << 4) + ln; if (qrow >= NTOK) qrow = NTOK - 1;
        #pragma unroll
        for (int kp = 0; kp < 2; kp++)
            aq[mi][kp] = *(const bf16x8*)(Qg + ((size_t)(b * NTOK + qrow)) * DIMC
                                          + h * HDIM + kp * 32 + (quad << 3));
    }
    int boff[2][4];
    #pragma unroll
    for (int mi = 0; mi < 2; mi++)
        #pragma unroll
        for (int reg = 0; reg < 4; reg++) {
            int rr = mbase + (mi << 4) + (quad << 2) + reg;
            if (rr >= NTOK) rr = NTOK - 1;
            boff[mi][reg] = rr * 768 + (ln << 2);
        }

    // P read swizzle constant (row = ln)
    const int pswz = ((ln >> 2) & 3) << 4;

    float rs[2][4] = {};
    f32x4 O[2][4];
    #pragma unroll
    for (int mi = 0; mi < 2; mi++)
        #pragma unroll
        for (int dt = 0; dt < 4; dt++) O[mi][dt] = (f32x4){0.f, 0.f, 0.f, 0.f};

    for (int j0 = 0; j0 < NTOK; j0 += 64) {
        __syncthreads();
        // K tile via async global->LDS, chunk-major
        #pragma unroll
        for (int l = 0; l < 2; l++) {
            int f = tid + (l << 8);                // 0..511
            int chunk = f >> 6, jr = f & 63;
            int krow = j0 + jr; if (krow >= NTOK) krow = NTOK - 1;
            gl_lds16(Kg + ((size_t)(b * NTOK + krow)) * DIMC + h * HDIM + chunk * 8,
                     KsL + f * 8);
        }
        // bias prefetch into registers
        uint2 bvv[2][4];
        #pragma unroll
        for (int mi = 0; mi < 2; mi++)
            #pragma unroll
            for (int reg = 0; reg < 4; reg++)
                bvv[mi][reg] = *(const uint2*)(bp + boff[mi][reg] + j0);
        // V tile transposed into XOR-swizzled LDS: elem V^T[d][j] at
        // d*72 + (j ^ ((d>>3)&7)*8)
        #pragma unroll
        for (int l = 0; l < 2; l++) {
            int u = tid + (l << 8);
            int jr = u >> 3, d0 = (u & 7) << 3;
            int vrow = j0 + jr; if (vrow >= NTOK) vrow = NTOK - 1;
            uint4 p = *(const uint4*)(Vg + ((size_t)(b * NTOK + vrow)) * DIMC + h * HDIM + d0);
            const u16* pe = (const u16*)&p;
            int jswz = jr ^ d0;                   // key = d0 (multiple of 8, <64)
            #pragma unroll
            for (int i = 0; i < 8; i++) VtL[(d0 + i) * 72 + jswz] = pe[i];
        }
        __syncthreads();

        // V B-frags (shared by both m-frags), b128 via swizzled offset
        bf16x8 bv[4][2];
        #pragma unroll
        for (int dt = 0; dt < 4; dt++) {
            int key8 = ((dt * 2 + (ln >> 3)) & 7) << 3;
            #pragma unroll
            for (int kp = 0; kp < 2; kp++) {
                int koff = (kp * 32 + (quad << 3)) ^ key8;
                bv[dt][kp] = *(const bf16x8*)&VtL[(dt * 16 + ln) * 72 + koff];
            }
        }

        // S = (Q/8) K^T, K-frags read once, both m-frags interleaved
        f32x4 s[2][4];
        #pragma unroll
        for (int mi = 0; mi < 2; mi++)
            #pragma unroll
            for (int nt = 0; nt < 4; nt++) s[mi][nt] = (f32x4){0.f, 0.f, 0.f, 0.f};
        __builtin_amdgcn_s_setprio(1);
        #pragma unroll
        for (int kp = 0; kp < 2; kp++)
            #pragma unroll
            for (int nt = 0; nt < 4; nt++) {
                bf16x8 bk = *(const bf16x8*)
                    &KsL[(((kp << 2) + quad) * 64 + nt * 16 + ln) * 8];
                s[0][nt] = __builtin_amdgcn_mfma_f32_16x16x32_bf16(aq[0][kp], bk, s[0][nt], 0, 0, 0);
                s[1][nt] = __builtin_amdgcn_mfma_f32_16x16x32_bf16(aq[1][kp], bk, s[1][nt], 0, 0, 0);
            }
        __builtin_amdgcn_s_setprio(0);

        #pragma unroll
        for (int mi = 0; mi < 2; mi++) {
            // + bias, exp(s - SMAX), accumulate row sums
            #pragma unroll
            for (int reg = 0; reg < 4; reg++) {
                uint2 bb = bvv[mi][reg];
                float p0 = __expf(s[mi][0][reg] + bflo(bb.x) - SMAX);
                float p1 = __expf(s[mi][1][reg] + bfhi(bb.x) - SMAX);
                float p2 = __expf(s[mi][2][reg] + bflo(bb.y) - SMAX);
                float p3 = __expf(s[mi][3][reg] + bfhi(bb.y) - SMAX);
                s[mi][0][reg] = p0; s[mi][1][reg] = p1;
                s[mi][2][reg] = p2; s[mi][3][reg] = p3;
                rs[mi][reg] += p0 + p1 + p2 + p3;
            }
            // P: C-layout -> A-layout through swizzled wave-private LDS:
            // write row quad*4+reg, col (nt^quad)*16 + ln
            u16* pwb = &Pw[(w << 1) + mi][0][0];
            #pragma unroll
            for (int nt = 0; nt < 4; nt++) {
                int colw = ((nt ^ quad) << 4) + ln;
                #pragma unroll
                for (int reg = 0; reg < 4; reg++)
                    pwb[((quad << 2) + reg) * 72 + colw] = f2bf(s[mi][nt][reg]);
            }
            bf16x8 ap[2];
            #pragma unroll
            for (int kp = 0; kp < 2; kp++) {
                int koff = (kp * 32 + (quad << 3)) ^ pswz;
                ap[kp] = *(const bf16x8*)&pwb[ln * 72 + koff];
            }
            // O += P V
            __builtin_amdgcn_s_setprio(1);
            #pragma unroll
            for (int dt = 0; dt < 4; dt++)
                #pragma unroll
                for (int kp = 0; kp < 2; kp++)
                    O[mi][dt] = __builtin_amdgcn_mfma_f32_16x16x32_bf16(
                        ap[kp], bv[dt][kp], O[mi][dt], 0, 0, 0);
            __builtin_amdgcn_s_setprio(0);
        }
    }

    // normalize + store
    #pragma unroll
    for (int mi = 0; mi < 2; mi++) {
        #pragma unroll
        for (int reg = 0; reg < 4; reg++) {
            float t = rs[mi][reg];
            #pragma unroll
            for (int mk = 8; mk >= 1; mk >>= 1) t += __shfl_xor(t, mk);
            float inv = 1.0f / t;
            int row = mbase + (mi << 4) + (quad << 2) + reg;
            if (row < NTOK) {
                #pragma unroll
                for (int dt = 0; dt < 4; dt++)
                    ctx[((size_t)(b * NTOK + row)) * DIMC + h * HDIM + dt * 16 + ln]
                        = f2bf(O[mi][dt][reg] * inv);
            }
        }
    }
}

// ---------------------------------------------------------------------------
extern "C" void kernel_launch(void* const* d_in, const int* in_sizes, int n_in,
                              void* d_out, int out_size, void* d_ws, size_t ws_size,
                              hipStream_t stream)
{
    const float* x        = (const float*)d_in[0];
    const float* temp_q   = (const float*)d_in[1];
    const float* target_q = (const float*)d_in[2];
    const float* q_w      = (const float*)d_in[3];
    const float* k_w      = (const float*)d_in[4];
    const float* v_w      = (const float*)d_in[5];
    const float* proj_w   = (const float*)d_in[6];
    const float* proj_b   = (const float*)d_in[7];
    const float* rpb      = (const float*)d_in[8];
    const float* rpbt     = (const float*)d_in[9];
    const float* pw1      = (const float*)d_in[10];
    const float* pb1      = (const float*)d_in[11];
    const float* pw2      = (const float*)d_in[12];
    const float* pb2      = (const float*)d_in[13];
    const float* tab      = (const float*)d_in[14];
    const int*   tidx     = (const int*)d_in[15];
    const int*   gidx     = (const int*)d_in[16];
    float* out = (float*)d_out;

    char* ws = (char*)d_ws;
    const size_t S = (size_t)MROWS * DIMC * sizeof(u16);          // 18,186,240
    const size_t SZB = (size_t)NHEAD * NTOK * 768 * sizeof(u16);  // 13,639,680
    u16* XB    = (u16*)(ws);           // also CTX (aliased, after KV gemm)
    u16* QB    = (u16*)(ws + S);       // also V (aliased, after Q gemm)
    u16* Q     = (u16*)(ws + 2 * S);
    u16* K     = (u16*)(ws + 3 * S);
    u16* V     = QB;
    u16* CTX   = XB;
    u16* BIAS2 = (u16*)(ws + 4 * S);
    u16* WT    = (u16*)(ws + 4 * S + SZB);                        // 4 x 768 x 768

    prep_kernel<<<dim3(PREP_ALL), 256, 0, stream>>>(
        x, temp_q, target_q, XB, QB,
        q_w, k_w, v_w, proj_w, WT,
        rpb, rpbt, tidx, gidx,
        pw1, pb1, pw2, pb2, tab, BIAS2);

    const u16* WTq = WT;
    const u16* WTk = WT + (size_t)DIMC * DIMC;    // k plane (v plane adjacent)
    const u16* WTp = WT + 3 * (size_t)DIMC * DIMC;

    gemm_bf16<0><<<dim3(6, 93), 256, 0, stream>>>(QB, WTq, nullptr, Q, nullptr, nullptr);
    gemm_bf16<1><<<dim3(12, 93), 256, 0, stream>>>(XB, WTk, nullptr, K, V, nullptr);
    attn_mfma<<<dim3(6, 12, 16), 256, 0, stream>>>(Q, K, V, BIAS2, CTX);
    gemm_bf16<2><<<dim3(6, 93), 256, 0, stream>>>(CTX, WTp, proj_b, nullptr, nullptr, out);
}

// Round 5
// 452.312 us; speedup vs baseline: 1.2189x; 1.0280x over previous
//
#include <hip/hip_runtime.h>

// Convattn: B=16, N=740 (256+484), C=768, H=12, hd=64. Inputs/outputs fp32.
// ws: XB/QB/Q/K/V/CTX bf16 (V aliases QB — safe ONLY because Q-GEMM and
// KV-GEMM are separate ordered launches; do NOT fuse them), BIAS2 bf16
// repacked [h][row][jb][ln][nt], WT bf16 (q-plane pre-scaled 0.125).

typedef unsigned short u16;
typedef short bf16x8 __attribute__((ext_vector_type(8)));
typedef float f32x4 __attribute__((ext_vector_type(4)));

#define BSZ   16
#define NTOK  740
#define NTMP  256
#define NTGT  484
#define DIMC  768
#define NHEAD 12
#define HDIM  64
#define MROWS (BSZ*NTOK)      // 11840
#define SMAX  16.0f           // fixed softmax max (scores bounded ~|6|)

__device__ __forceinline__ float bf2f(u16 u) {
    return __uint_as_float(((unsigned int)u) << 16);
}
__device__ __forceinline__ float bflo(unsigned int u) {
    return __uint_as_float(u << 16);
}
__device__ __forceinline__ float bfhi(unsigned int u) {
    return __uint_as_float(u & 0xffff0000u);
}
__device__ __forceinline__ u16 f2bf(float f) {
    unsigned int u = __float_as_uint(f);
    u += 0x7fffu + ((u >> 16) & 1u);   // RNE
    return (u16)(u >> 16);
}

// async 16B global -> LDS (gfx950). LDS dest must be wave base + lane*16.
__device__ __forceinline__ void gl_lds16(const u16* g, u16* l) {
    __builtin_amdgcn_global_load_lds(
        (const __attribute__((address_space(1))) unsigned int*)(unsigned long long)g,
        (__attribute__((address_space(3))) unsigned int*)(unsigned int)(unsigned long long)l,
        16, 0, 0);
}

// repacked bias offset: [h][i][jb][ln][nt]
__device__ __forceinline__ size_t b2off(int h, int i, int j) {
    return ((size_t)(h * NTOK + i)) * 768 + ((j >> 6) << 6) + ((j & 15) << 2) + ((j >> 4) & 3);
}

// ---------------------------------------------------------------------------
// Fused prep kernel: MLP first (long serial blocks overlap BW sections),
// then convert (2 chunks/thread = 8 float4 loads in flight for ILP),
// weight-transpose, bias-diag.
// grid = 484 + 2220 + 576 + 2220 = 5500.
// ---------------------------------------------------------------------------
#define PREP_MLP  484
#define PREP_CONV (PREP_MLP + 2220)    // 2704
#define PREP_TRW  (PREP_CONV + 576)    // 3280
#define PREP_ALL  (PREP_TRW + 2220)    // 5500

__global__ __launch_bounds__(256) void prep_kernel(
    const float* __restrict__ x, const float* __restrict__ tq,
    const float* __restrict__ gq, u16* __restrict__ XB, u16* __restrict__ QB,
    const float* __restrict__ w0, const float* __restrict__ w1,
    const float* __restrict__ w2, const float* __restrict__ w3,
    u16* __restrict__ Wt,
    const float* __restrict__ rpb, const float* __restrict__ rpbt,
    const int* __restrict__ tidx, const int* __restrict__ gidx,
    const float* __restrict__ pw1, const float* __restrict__ pb1,
    const float* __restrict__ pw2, const float* __restrict__ pb2,
    const float* __restrict__ tab, u16* __restrict__ bias)
{
    __shared__ float T[64][65];
    const int blk = blockIdx.x;
    const int tid = threadIdx.x;

    if (blk < PREP_MLP) {
        // ----- cross-bias MLP (proven body; VGPR16/SGPR96 s_load batching) --
        int g = blk;                      // 0..483
        int t = tid;                      // 0..255
        float a  = tab[(g * NTMP + t) * 2 + 0];
        float bb = tab[(g * NTMP + t) * 2 + 1];
        float acc[NHEAD];
        #pragma unroll
        for (int h = 0; h < NHEAD; h++) acc[h] = pb2[h];
        for (int k = 0; k < 512; k++) {
            float hid = fmaxf(a * pw1[k] + bb * pw1[512 + k] + pb1[k], 0.0f);
            #pragma unroll
            for (int h = 0; h < NHEAD; h++) acc[h] += hid * pw2[k * NHEAD + h];
        }
        #pragma unroll
        for (int h = 0; h < NHEAD; h++) {
            u16 v = f2bf(acc[h]);
            bias[b2off(h, t, NTMP + g)] = v;   // top-right
            bias[b2off(h, NTMP + g, t)] = v;   // bottom-left
        }
    } else if (blk < PREP_CONV) {
        // ----- fp32 -> bf16 convert: XB, QB. 2 chunks/thread, loads first --
        int t0 = (blk - PREP_MLP) * 512 + tid;
        int t1 = t0 + 256;
        const float* xs0 = x + (size_t)t0 * 8;
        const float* xs1 = x + (size_t)t1 * 8;
        float4 xa0 = ((const float4*)xs0)[0], xa1 = ((const float4*)xs0)[1];
        float4 xb0 = ((const float4*)xs1)[0], xb1 = ((const float4*)xs1)[1];
        int r0 = t0 / 96, cc0 = (t0 - r0 * 96) * 8;
        int b0 = r0 / NTOK, n0 = r0 - b0 * NTOK;
        const float* qs0 = (n0 < NTMP)
                         ? tq + ((size_t)(b0 * NTMP + n0)) * DIMC + cc0
                         : gq + ((size_t)(b0 * NTGT + (n0 - NTMP))) * DIMC + cc0;
        int r1 = t1 / 96, cc1 = (t1 - r1 * 96) * 8;
        int b1 = r1 / NTOK, n1 = r1 - b1 * NTOK;
        const float* qs1 = (n1 < NTMP)
                         ? tq + ((size_t)(b1 * NTMP + n1)) * DIMC + cc1
                         : gq + ((size_t)(b1 * NTGT + (n1 - NTMP))) * DIMC + cc1;
        float4 qa0 = ((const float4*)qs0)[0], qa1 = ((const float4*)qs0)[1];
        float4 qb0 = ((const float4*)qs1)[0], qb1 = ((const float4*)qs1)[1];
        {
            u16 e[8] = {f2bf(xa0.x), f2bf(xa0.y), f2bf(xa0.z), f2bf(xa0.w),
                        f2bf(xa1.x), f2bf(xa1.y), f2bf(xa1.z), f2bf(xa1.w)};
            *(uint4*)(XB + (size_t)t0 * 8) = *(uint4*)e;
        }
        {
            u16 e[8] = {f2bf(xb0.x), f2bf(xb0.y), f2bf(xb0.z), f2bf(xb0.w),
                        f2bf(xb1.x), f2bf(xb1.y), f2bf(xb1.z), f2bf(xb1.w)};
            *(uint4*)(XB + (size_t)t1 * 8) = *(uint4*)e;
        }
        {
            u16 e[8] = {f2bf(qa0.x), f2bf(qa0.y), f2bf(qa0.z), f2bf(qa0.w),
                        f2bf(qa1.x), f2bf(qa1.y), f2bf(qa1.z), f2bf(qa1.w)};
            *(uint4*)(QB + (size_t)r0 * DIMC + cc0) = *(uint4*)e;
        }
        {
            u16 e[8] = {f2bf(qb0.x), f2bf(qb0.y), f2bf(qb0.z), f2bf(qb0.w),
                        f2bf(qb1.x), f2bf(qb1.y), f2bf(qb1.z), f2bf(qb1.w)};
            *(uint4*)(QB + (size_t)r1 * DIMC + cc1) = *(uint4*)e;
        }
    } else if (blk < PREP_TRW) {
        // ----- weight transpose + bf16 (z=0 scaled 1/8) -----
        int t = blk - PREP_CONV;          // 0..575
        int z = t / 144, rem = t - z * 144;
        int bx = rem % 12, by = rem / 12;
        const float* src = (z == 0) ? w0 : (z == 1) ? w1 : (z == 2) ? w2 : w3;
        const float scale = (z == 0) ? 0.125f : 1.0f;
        u16* dst = Wt + (size_t)z * DIMC * DIMC;
        int out0 = bx * 64, in0 = by * 64;
        #pragma unroll
        for (int l = 0; l < 4; l++) {
            int u = tid + (l << 8);
            int r = u >> 4, c4 = (u & 15) << 2;
            float4 p = *(const float4*)(src + (size_t)(in0 + r) * DIMC + out0 + c4);
            T[r][c4] = p.x; T[r][c4 + 1] = p.y; T[r][c4 + 2] = p.z; T[r][c4 + 3] = p.w;
        }
        __syncthreads();
        #pragma unroll
        for (int l = 0; l < 2; l++) {
            int u = tid + (l << 8);
            int r = u >> 3, c8 = (u & 7) << 3;
            u16 e[8];
            #pragma unroll
            for (int i = 0; i < 8; i++) e[i] = f2bf(T[c8 + i][r] * scale);
            *(uint4*)(dst + (size_t)(out0 + r) * DIMC + in0 + c8) = *(uint4*)e;
        }
    } else {
        // ----- bias diagonal blocks + padding -----
        int t = blk - PREP_TRW;           // 0..2219
        int jb = t % 3, i = t / 3;
        int j = jb * 256 + tid;
        u16 vals[NHEAD];
        if (j >= NTOK) {
            u16 neg = f2bf(-1e30f);
            #pragma unroll
            for (int h = 0; h < NHEAD; h++) vals[h] = neg;
        } else if (i < NTMP && j < NTMP) {
            int idx = tidx[i * NTMP + j];
            #pragma unroll
            for (int h = 0; h < NHEAD; h++) vals[h] = f2bf(rpbt[idx * NHEAD + h]);
        } else if (i >= NTMP && j >= NTMP) {
            int idx = gidx[(i - NTMP) * NTGT + (j - NTMP)];
            #pragma unroll
            for (int h = 0; h < NHEAD; h++) vals[h] = f2bf(rpb[idx * NHEAD + h]);
        } else {
            return;  // cross region
        }
        #pragma unroll
        for (int h = 0; h < NHEAD; h++) bias[b2off(h, i, j)] = vals[h];
    }
}

// ---------------------------------------------------------------------------
// bf16 MFMA GEMM, BM=BN=128, BK=64, chunk-major LDS, gl_lds w16.
// 2-phase double-buffered K-loop; bijective XCD-chunked blockIdx swizzle.
// MODE 0: out bf16 -> C0. MODE 1: KV (bx<6 -> K, else V). MODE 2: fp32+pb.
// NOTE: MODE 0 (reads QB) and MODE 1 (writes V==QB) MUST be separate launches.
// ---------------------------------------------------------------------------
template<int MODE>
__global__ __launch_bounds__(256) void gemm_bf16(
    const u16* __restrict__ A, const u16* __restrict__ Wt,
    const float* __restrict__ pb, u16* __restrict__ C0,
    u16* __restrict__ C1, float* __restrict__ Cf)
{
    __shared__ __align__(16) u16 As[2][8192];   // [buf][chunk(8)][row(128)][8]
    __shared__ __align__(16) u16 Bs[2][8192];
    const int tid = threadIdx.x;
    const int lane = tid & 63, w = tid >> 6;
    const int quad = lane >> 4, ln = lane & 15;

    // XCD-chunked bijective swizzle (hw dispatch id -> logical wg).
    const int gx = gridDim.x;
    const int nwg = gx * (int)gridDim.y;
    const int flat = blockIdx.y * gx + blockIdx.x;
    const int q = nwg >> 3, r = nwg & 7;
    const int xcd = flat & 7, sidx = flat >> 3;
    const int wg = (xcd < r) ? xcd * (q + 1) + sidx
                             : r * (q + 1) + (xcd - r) * q + sidx;
    const int by = wg / gx, bx = wg - by * gx;

    const int m0 = by << 7;
    const int wm = (w >> 1) << 6, wn = (w & 1) << 6;

    const int nn = bx << 7;
    const u16* Wbase = Wt + (size_t)nn * DIMC;
    u16* Cb;
    int col0;
    if (MODE == 1) {
        if (nn < DIMC) { col0 = nn; Cb = C0; }
        else           { col0 = nn - DIMC; Cb = C1; }
    } else {
        col0 = nn; Cb = C0;
    }

    f32x4 acc[4][4];
    #pragma unroll
    for (int i = 0; i < 4; i++)
        #pragma unroll
        for (int j = 0; j < 4; j++)
            acc[i][j] = (f32x4){0.f, 0.f, 0.f, 0.f};

#define STAGE(s, k0) do {                                                     \
    _Pragma("unroll")                                                         \
    for (int l = 0; l < 4; l++) {                                             \
        int f = tid + (l << 8);          /* 0..1023 */                        \
        int c8 = f >> 7, rr = f & 127;                                        \
        int grow = m0 + rr; if (grow >= MROWS) grow = MROWS - 1;              \
        gl_lds16(A + (size_t)grow * DIMC + (k0) + c8 * 8, &As[s][f * 8]);     \
        gl_lds16(Wbase + (size_t)rr * DIMC + (k0) + c8 * 8, &Bs[s][f * 8]);   \
    } } while (0)

#define COMPUTE(s) do {                                                       \
    _Pragma("unroll")                                                         \
    for (int kp = 0; kp < 2; kp++) {                                          \
        bf16x8 af[4], bfr[4];                                                 \
        _Pragma("unroll")                                                     \
        for (int mt = 0; mt < 4; mt++)                                        \
            af[mt] = *(const bf16x8*)                                         \
                &As[s][(((kp << 2) + quad) * 128 + wm + mt * 16 + ln) * 8];   \
        _Pragma("unroll")                                                     \
        for (int nt = 0; nt < 4; nt++)                                        \
            bfr[nt] = *(const bf16x8*)                                        \
                &Bs[s][(((kp << 2) + quad) * 128 + wn + nt * 16 + ln) * 8];   \
        _Pragma("unroll")                                                     \
        for (int mt = 0; mt < 4; mt++)                                        \
            _Pragma("unroll")                                                 \
            for (int nt = 0; nt < 4; nt++)                                    \
                acc[mt][nt] = __builtin_amdgcn_mfma_f32_16x16x32_bf16(        \
                    af[mt], bfr[nt], acc[mt][nt], 0, 0, 0);                   \
    } } while (0)

    // prologue: stage tile 0, drain, then 2-phase pipeline over 12 K-tiles
    STAGE(0, 0);
    __syncthreads();
    #pragma unroll 1
    for (int t = 0; t < 12; t += 2) {
        STAGE(1, (t + 1) << 6);          // t<=10 so t+1<=11: always valid
        COMPUTE(0);
        __syncthreads();                 // drains vmcnt(0): tile t+1 ready
        if (t < 10) STAGE(0, (t + 2) << 6);
        COMPUTE(1);
        __syncthreads();
    }

#undef STAGE
#undef COMPUTE

    #pragma unroll
    for (int mt = 0; mt < 4; mt++) {
        #pragma unroll
        for (int reg = 0; reg < 4; reg++) {
            int grow = m0 + wm + mt * 16 + (quad << 2) + reg;
            if (grow >= MROWS) continue;
            #pragma unroll
            for (int nt = 0; nt < 4; nt++) {
                int gcol = col0 + wn + nt * 16 + ln;
                float v = acc[mt][nt][reg];
                if (MODE == 2) {
                    Cf[(size_t)grow * DIMC + gcol] = v + pb[gcol];
                } else {
                    Cb[(size_t)grow * DIMC + gcol] = f2bf(v);
                }
            }
        }
    }
}

// ---------------------------------------------------------------------------
// Flash MFMA attention, fixed-max softmax. 64 Q-rows/block, each of 4 waves
// owns ONE 16-row m-frag: grid 2304 blocks (9/CU of work), LDS 26.6 KB
// (6 blocks/CU resident) -> 3x the TLP of the 128-row version, on a
// latency-bound kernel. h-major XCD-chunked remap (2304 = 8*288; 12
// consecutive blocks share (h,b) so K/V 379 KB stays L2-hot).
// grid (12, 12, 16).
// ---------------------------------------------------------------------------
__global__ __launch_bounds__(256) void attn_mfma(
    const u16* __restrict__ Qg, const u16* __restrict__ Kg,
    const u16* __restrict__ Vg, const u16* __restrict__ bias,
    u16* __restrict__ ctx)
{
    __shared__ __align__(16) u16 KsL[4096];        // [chunk(8)][jr(64)][8]
    __shared__ __align__(16) u16 VtL[64 * 72];     // [d][j^swz], stride 72
    __shared__ __align__(16) u16 Pw[4][16][72];    // [w][m][k^swz]

    const int tid = threadIdx.x;
    const int lane = tid & 63, w = tid >> 6;
    const int quad = lane >> 4, ln = lane & 15;

    // h-major XCD-chunked remap (bijective: 2304 = 8 * 288).
    const int flat = (blockIdx.z * 12 + blockIdx.y) * 12 + blockIdx.x;
    const int wg = (flat & 7) * 288 + (flat >> 3);
    const int h = wg / 192;
    const int rem = wg - h * 192;
    const int b = rem / 12;
    const int q0 = (rem - b * 12) << 6;

    const int mbase = q0 + (w << 4);               // wave's 16 rows
    const u16* bp = bias + ((size_t)h * NTOK) * 768;

    // Q fragments (A-layout), held for the whole kernel
    bf16x8 aq[2];
    {
        int qrow = mbase + ln; if (qrow >= NTOK) qrow = NTOK - 1;
        #pragma unroll
        for (int kp = 0; kp < 2; kp++)
            aq[kp] = *(const bf16x8*)(Qg + ((size_t)(b * NTOK + qrow)) * DIMC
                                      + h * HDIM + kp * 32 + (quad << 3));
    }
    int boff[4];
    #pragma unroll
    for (int reg = 0; reg < 4; reg++) {
        int rr = mbase + (quad << 2) + reg;
        if (rr >= NTOK) rr = NTOK - 1;
        boff[reg] = rr * 768 + (ln << 2);
    }

    // P read swizzle constant (row = ln)
    const int pswz = ((ln >> 2) & 3) << 4;

    float rs[4] = {};
    f32x4 O[4];
    #pragma unroll
    for (int dt = 0; dt < 4; dt++) O[dt] = (f32x4){0.f, 0.f, 0.f, 0.f};

    for (int j0 = 0; j0 < NTOK; j0 += 64) {
        __syncthreads();
        // K tile via async global->LDS, chunk-major
        #pragma unroll
        for (int l = 0; l < 2; l++) {
            int f = tid + (l << 8);                // 0..511
            int chunk = f >> 6, jr = f & 63;
            int krow = j0 + jr; if (krow >= NTOK) krow = NTOK - 1;
            gl_lds16(Kg + ((size_t)(b * NTOK + krow)) * DIMC + h * HDIM + chunk * 8,
                     KsL + f * 8);
        }
        // bias prefetch into registers
        uint2 bvv[4];
        #pragma unroll
        for (int reg = 0; reg < 4; reg++)
            bvv[reg] = *(const uint2*)(bp + boff[reg] + j0);
        // V tile transposed into XOR-swizzled LDS: elem V^T[d][j] at
        // d*72 + (j ^ ((d>>3)&7)*8)
        #pragma unroll
        for (int l = 0; l < 2; l++) {
            int u = tid + (l << 8);
            int jr = u >> 3, d0 = (u & 7) << 3;
            int vrow = j0 + jr; if (vrow >= NTOK) vrow = NTOK - 1;
            uint4 p = *(const uint4*)(Vg + ((size_t)(b * NTOK + vrow)) * DIMC + h * HDIM + d0);
            const u16* pe = (const u16*)&p;
            int jswz = jr ^ d0;                   // key = d0 (multiple of 8, <64)
            #pragma unroll
            for (int i = 0; i < 8; i++) VtL[(d0 + i) * 72 + jswz] = pe[i];
        }
        __syncthreads();

        // V B-frags, b128 via swizzled offset
        bf16x8 bv[4][2];
        #pragma unroll
        for (int dt = 0; dt < 4; dt++) {
            int key8 = ((dt * 2 + (ln >> 3)) & 7) << 3;
            #pragma unroll
            for (int kp = 0; kp < 2; kp++) {
                int koff = (kp * 32 + (quad << 3)) ^ key8;
                bv[dt][kp] = *(const bf16x8*)&VtL[(dt * 16 + ln) * 72 + koff];
            }
        }

        // S = (Q/8) K^T
        f32x4 s[4];
        #pragma unroll
        for (int nt = 0; nt < 4; nt++) s[nt] = (f32x4){0.f, 0.f, 0.f, 0.f};
        __builtin_amdgcn_s_setprio(1);
        #pragma unroll
        for (int kp = 0; kp < 2; kp++)
            #pragma unroll
            for (int nt = 0; nt < 4; nt++) {
                bf16x8 bk = *(const bf16x8*)
                    &KsL[(((kp << 2) + quad) * 64 + nt * 16 + ln) * 8];
                s[nt] = __builtin_amdgcn_mfma_f32_16x16x32_bf16(aq[kp], bk, s[nt], 0, 0, 0);
            }
        __builtin_amdgcn_s_setprio(0);

        // + bias, exp(s - SMAX), accumulate row sums
        #pragma unroll
        for (int reg = 0; reg < 4; reg++) {
            uint2 bb = bvv[reg];
            float p0 = __expf(s[0][reg] + bflo(bb.x) - SMAX);
            float p1 = __expf(s[1][reg] + bfhi(bb.x) - SMAX);
            float p2 = __expf(s[2][reg] + bflo(bb.y) - SMAX);
            float p3 = __expf(s[3][reg] + bfhi(bb.y) - SMAX);
            s[0][reg] = p0; s[1][reg] = p1;
            s[2][reg] = p2; s[3][reg] = p3;
            rs[reg] += p0 + p1 + p2 + p3;
        }
        // P: C-layout -> A-layout through swizzled wave-private LDS:
        // write row quad*4+reg, col (nt^quad)*16 + ln
        u16* pwb = &Pw[w][0][0];
        #pragma unroll
        for (int nt = 0; nt < 4; nt++) {
            int colw = ((nt ^ quad) << 4) + ln;
            #pragma unroll
            for (int reg = 0; reg < 4; reg++)
                pwb[((quad << 2) + reg) * 72 + colw] = f2bf(s[nt][reg]);
        }
        bf16x8 ap[2];
        #pragma unroll
        for (int kp = 0; kp < 2; kp++) {
            int koff = (kp * 32 + (quad << 3)) ^ pswz;
            ap[kp] = *(const bf16x8*)&pwb[ln * 72 + koff];
        }
        // O += P V
        __builtin_amdgcn_s_setprio(1);
        #pragma unroll
        for (int dt = 0; dt < 4; dt++)
            #pragma unroll
            for (int kp = 0; kp < 2; kp++)
                O[dt] = __builtin_amdgcn_mfma_f32_16x16x32_bf16(
                    ap[kp], bv[dt][kp], O[dt], 0, 0, 0);
        __builtin_amdgcn_s_setprio(0);
    }

    // normalize + store
    #pragma unroll
    for (int reg = 0; reg < 4; reg++) {
        float t = rs[reg];
        #pragma unroll
        for (int mk = 8; mk >= 1; mk >>= 1) t += __shfl_xor(t, mk);
        float inv = 1.0f / t;
        int row = mbase + (quad << 2) + reg;
        if (row < NTOK) {
            #pragma unroll
            for (int dt = 0; dt < 4; dt++)
                ctx[((size_t)(b * NTOK + row)) * DIMC + h * HDIM + dt * 16 + ln]
                    = f2bf(O[dt][reg] * inv);
        }
    }
}

// ---------------------------------------------------------------------------
extern "C" void kernel_launch(void* const* d_in, const int* in_sizes, int n_in,
                              void* d_out, int out_size, void* d_ws, size_t ws_size,
                              hipStream_t stream)
{
    const float* x        = (const float*)d_in[0];
    const float* temp_q   = (const float*)d_in[1];
    const float* target_q = (const float*)d_in[2];
    const float* q_w      = (const float*)d_in[3];
    const float* k_w      = (const float*)d_in[4];
    const float* v_w      = (const float*)d_in[5];
    const float* proj_w   = (const float*)d_in[6];
    const float* proj_b   = (const float*)d_in[7];
    const float* rpb      = (const float*)d_in[8];
    const float* rpbt     = (const float*)d_in[9];
    const float* pw1      = (const float*)d_in[10];
    const float* pb1      = (const float*)d_in[11];
    const float* pw2      = (const float*)d_in[12];
    const float* pb2      = (const float*)d_in[13];
    const float* tab      = (const float*)d_in[14];
    const int*   tidx     = (const int*)d_in[15];
    const int*   gidx     = (const int*)d_in[16];
    float* out = (float*)d_out;

    char* ws = (char*)d_ws;
    const size_t S = (size_t)MROWS * DIMC * sizeof(u16);          // 18,186,240
    const size_t SZB = (size_t)NHEAD * NTOK * 768 * sizeof(u16);  // 13,639,680
    u16* XB    = (u16*)(ws);           // also CTX (aliased, after KV gemm)
    u16* QB    = (u16*)(ws + S);       // also V (aliased, after Q gemm)
    u16* Q     = (u16*)(ws + 2 * S);
    u16* K     = (u16*)(ws + 3 * S);
    u16* V     = QB;
    u16* CTX   = XB;
    u16* BIAS2 = (u16*)(ws + 4 * S);
    u16* WT    = (u16*)(ws + 4 * S + SZB);                        // 4 x 768 x 768

    prep_kernel<<<dim3(PREP_ALL), 256, 0, stream>>>(
        x, temp_q, target_q, XB, QB,
        q_w, k_w, v_w, proj_w, WT,
        rpb, rpbt, tidx, gidx,
        pw1, pb1, pw2, pb2, tab, BIAS2);

    const u16* WTq = WT;
    const u16* WTk = WT + (size_t)DIMC * DIMC;    // k plane (v plane adjacent)
    const u16* WTp = WT + 3 * (size_t)DIMC * DIMC;

    gemm_bf16<0><<<dim3(6, 93), 256, 0, stream>>>(QB, WTq, nullptr, Q, nullptr, nullptr);
    gemm_bf16<1><<<dim3(12, 93), 256, 0, stream>>>(XB, WTk, nullptr, K, V, nullptr);
    attn_mfma<<<dim3(12, 12, 16), 256, 0, stream>>>(Q, K, V, BIAS2, CTX);
    gemm_bf16<2><<<dim3(6, 93), 256, 0, stream>>>(CTX, WTp, proj_b, nullptr, nullptr, out);
}